// Round 15
// baseline (194.094 us; speedup 1.0000x reference)
//
#include <hip/hip_runtime.h>
#include <hip/hip_bf16.h>

#define BN_EPS 1e-5f
#define FIXSCALE 16777216.0f            // 2^24
#define FIXINV   5.9604644775390625e-08 // 2^-24
#define LOWMASK  0xFFFFFFFFFFULL        // low 40 bits

typedef __attribute__((ext_vector_type(8))) short bf16x8;
typedef __attribute__((ext_vector_type(4))) float f32x4;

__device__ __forceinline__ unsigned short bfu(float v) {
  return __bfloat16_as_ushort(__float2bfloat16(v));
}
__device__ __forceinline__ unsigned int pk_bf2(float a, float b) {
  return (unsigned int)bfu(a) | ((unsigned int)bfu(b) << 16);
}
__device__ __forceinline__ float bf_lo(unsigned int u) { return __uint_as_float(u << 16); }
__device__ __forceinline__ float bf_hi(unsigned int u) { return __uint_as_float(u & 0xFFFF0000u); }

__device__ __forceinline__ void fma8(float* a, uint4 u, float c) {
  a[0] += bf_lo(u.x) * c; a[1] += bf_hi(u.x) * c;
  a[2] += bf_lo(u.y) * c; a[3] += bf_hi(u.y) * c;
  a[4] += bf_lo(u.z) * c; a[5] += bf_hi(u.z) * c;
  a[6] += bf_lo(u.w) * c; a[7] += bf_hi(u.w) * c;
}

__device__ __forceinline__ float4 load4(const float* p) { return *(const float4*)p; }
__device__ __forceinline__ float4 load4(const unsigned short* p) {
  uint2 u = *(const uint2*)p;
  return make_float4(bf_lo(u.x), bf_hi(u.x), bf_lo(u.y), bf_hi(u.y));
}

template <int FIN, int FOUT>
constexpr int gemm_lds_bytes() {
  int stage = (64 * (FIN + 8) + FOUT * (FIN + 8)) * 2;  // shorts*2 = bytes
  int cb = 64 * (FOUT + 4) * 4;
  return stage > cb ? stage : cb;
}

// ---------------- prep: zero packed + weight transpose->bf16 ----------------

__global__ void prep_k(const float* __restrict__ W1, const float* __restrict__ W2,
                       const float* __restrict__ W3, unsigned short* __restrict__ wt1,
                       unsigned short* __restrict__ wt2, unsigned short* __restrict__ wt3,
                       unsigned long long* __restrict__ packed, int n) {
  int idx = blockIdx.x * 256 + threadIdx.x;
  if (idx < n) packed[idx] = 0ULL;
  if (idx < 128 * 128) {
    int c = idx >> 7, k = idx & 127;
    wt1[idx] = bfu(W1[k * 128 + c]);
  } else if (idx < 128 * 128 + 128 * 64) {
    int i2 = idx - 128 * 128;
    int c = i2 >> 7, k = i2 & 127;  // wt2: [64][128]
    wt2[i2] = bfu(W2[k * 64 + c]);
  } else if (idx < 128 * 128 + 128 * 64 + 64 * 32) {
    int i2 = idx - 128 * 128 - 128 * 64;
    int c = i2 >> 6, k = i2 & 63;   // wt3: [32][64]
    wt3[i2] = bfu(W3[k * 32 + c]);
  }
}

// ---------------- CSR build (1 returning atomic/edge; 2 edges/thread; 0 LDS) ----------

__global__ void hist64_k(const int* __restrict__ dst, const float* __restrict__ w,
                         unsigned long long* __restrict__ packed, int* __restrict__ rank, int e) {
  int i = (blockIdx.x * blockDim.x + threadIdx.x) * 2;
  if (i + 1 < e) {
    int2 d2 = *(const int2*)(dst + i);
    float2 w2 = *(const float2*)(w + i);
    unsigned long long a0 = (1ULL << 40) | (unsigned long long)__float2uint_rn(w2.x * FIXSCALE);
    unsigned long long a1 = (1ULL << 40) | (unsigned long long)__float2uint_rn(w2.y * FIXSCALE);
    unsigned long long o0 = atomicAdd(&packed[d2.x], a0);
    unsigned long long o1 = atomicAdd(&packed[d2.y], a1);
    *(int2*)(rank + i) = make_int2((int)(o0 >> 40), (int)(o1 >> 40));
  } else if (i < e) {
    unsigned long long fw = (unsigned long long)__float2uint_rn(w[i] * FIXSCALE);
    unsigned long long old = atomicAdd(&packed[dst[i]], (1ULL << 40) | fw);
    rank[i] = (int)(old >> 40);
  }
}

// ---------------- MFMA GEMM ----------------

template <typename TIN, int FIN, int FOUT, bool BNIN, bool GATHER>
__global__ __launch_bounds__(256) void gemm_mfma_k(
    const TIN* __restrict__ H, const int* __restrict__ xidx,
    const float* __restrict__ scale, const float* __restrict__ shift,
    const unsigned short* __restrict__ WtG, unsigned short* __restrict__ out, int n) {
  constexpr int C4 = FIN / 4;
  constexpr int ldH = FIN + 8;
  constexpr int ldW = FIN + 8;
  constexpr int ldC = FOUT + 4;
  constexpr int NCT = FOUT / 16;
  constexpr int NK = FIN / 32;
  constexpr int HT_SH = 64 * ldH;

  __shared__ __align__(16) char smem[gemm_lds_bytes<FIN, FOUT>()];
  unsigned short* Ht = (unsigned short*)smem;
  unsigned short* Wt = (unsigned short*)smem + HT_SH;
  float* Cs = (float*)smem;

  const int t = threadIdx.x;
  const int r0 = blockIdx.x * 64;

  constexpr int NH = 64 * C4 / 256;
#pragma unroll
  for (int i = 0; i < NH; ++i) {
    int idx = t + 256 * i;
    int r = idx / C4, c4 = idx % C4;
    int gr = r0 + r;
    if (gr < n) {
      int srow = GATHER ? xidx[gr] : gr;
      float4 v = load4(H + (size_t)srow * FIN + c4 * 4);
      if (BNIN) {
        float4 sc = *(const float4*)(scale + c4 * 4);
        float4 sh = *(const float4*)(shift + c4 * 4);
        v.x = fmaxf(v.x * sc.x + sh.x, 0.f);
        v.y = fmaxf(v.y * sc.y + sh.y, 0.f);
        v.z = fmaxf(v.z * sc.z + sh.z, 0.f);
        v.w = fmaxf(v.w * sc.w + sh.w, 0.f);
      }
      ushort4 p;
      p.x = bfu(v.x); p.y = bfu(v.y); p.z = bfu(v.z); p.w = bfu(v.w);
      *(ushort4*)&Ht[r * ldH + c4 * 4] = p;
    }
  }
  constexpr int NWU = FOUT * FIN / 8 / 256;
#pragma unroll
  for (int i = 0; i < NWU; ++i) {
    int idx = t + 256 * i;
    int wr = idx / (FIN / 8), w8 = idx % (FIN / 8);
    *(uint4*)&Wt[wr * ldW + w8 * 8] = *(const uint4*)&WtG[wr * FIN + w8 * 8];
  }
  __syncthreads();

  const int w = t >> 6;
  const int l = t & 63;
  const int l15 = l & 15;
  const int kg = l >> 4;
  const int arow = w * 16 + l15;

  f32x4 acc[NCT];
#pragma unroll
  for (int c = 0; c < NCT; ++c) acc[c] = (f32x4){0.f, 0.f, 0.f, 0.f};

#pragma unroll
  for (int kk = 0; kk < NK; ++kk) {
    bf16x8 a = *(const bf16x8*)&Ht[arow * ldH + kk * 32 + kg * 8];
#pragma unroll
    for (int c = 0; c < NCT; ++c) {
      bf16x8 b = *(const bf16x8*)&Wt[(c * 16 + l15) * ldW + kk * 32 + kg * 8];
      acc[c] = __builtin_amdgcn_mfma_f32_16x16x32_bf16(a, b, acc[c], 0, 0, 0);
    }
  }
  __syncthreads();  // done reading Ht/Wt; Cs overlays them

#pragma unroll
  for (int c = 0; c < NCT; ++c)
#pragma unroll
    for (int m = 0; m < 4; ++m)
      Cs[(w * 16 + kg * 4 + m) * ldC + c * 16 + l15] = acc[c][m];
  __syncthreads();

  constexpr int NU = 64 * FOUT / 8 / 256;
#pragma unroll
  for (int i = 0; i < NU; ++i) {
    int u = t + 256 * i;
    int r = u / (FOUT / 8), c8 = u % (FOUT / 8);
    int gr = r0 + r;
    if (gr < n) {
      const float* p = &Cs[r * ldC + c8 * 8];
      float4 v0 = *(const float4*)p;
      float4 v1 = *(const float4*)(p + 4);
      uint4 o;
      o.x = pk_bf2(v0.x, v0.y); o.y = pk_bf2(v0.z, v0.w);
      o.z = pk_bf2(v1.x, v1.y); o.w = pk_bf2(v1.z, v1.w);
      *(uint4*)&out[(size_t)gr * FOUT + c8 * 8] = o;
    }
  }
}

// ---------------- scans + scatter ----------------

__global__ void scan_partial_k(const unsigned long long* __restrict__ packed,
                               int* __restrict__ bsum, float* __restrict__ dinv, int n) {
  __shared__ int s[256];
  int idx = blockIdx.x * 256 + threadIdx.x;
  unsigned long long p = (idx < n) ? packed[idx] : 0ULL;
  if (idx < n)
    dinv[idx] = rsqrtf(1.0f + (float)((double)(p & LOWMASK) * FIXINV));
  s[threadIdx.x] = (int)(p >> 40);
  __syncthreads();
  for (int off = 128; off > 0; off >>= 1) {
    if (threadIdx.x < off) s[threadIdx.x] += s[threadIdx.x + off];
    __syncthreads();
  }
  if (threadIdx.x == 0) bsum[blockIdx.x] = s[0];
}

__global__ void scan_final_k(const unsigned long long* __restrict__ packed,
                             const int* __restrict__ bsum, int* __restrict__ rowptr,
                             int n, int nb) {
  __shared__ int sb[256];
  __shared__ int s[256];
  const int b = blockIdx.x, t = threadIdx.x;

  int bv = (t < nb) ? bsum[t] : 0;
  sb[t] = bv;
  __syncthreads();
  for (int off = 1; off < 256; off <<= 1) {
    int u = (t >= off) ? sb[t - off] : 0;
    __syncthreads();
    sb[t] += u;
    __syncthreads();
  }
  const int blockbase = (b == 0) ? 0 : sb[b - 1];
  if (b == 0 && t == 0) rowptr[n] = sb[nb - 1];

  int idx = b * 256 + t;
  int v = (idx < n) ? (int)(packed[idx] >> 40) : 0;
  s[t] = v;
  __syncthreads();
  for (int off = 1; off < 256; off <<= 1) {
    int u = (t >= off) ? s[t - off] : 0;
    __syncthreads();
    s[t] += u;
    __syncthreads();
  }
  if (idx < n) rowptr[idx] = blockbase + s[t] - v;
}

__global__ void scatter_nb_k(const int* __restrict__ src, const int* __restrict__ dst,
                             const float* __restrict__ w, const int* __restrict__ rank,
                             const float* __restrict__ dinv, const int* __restrict__ rowptr,
                             int2* __restrict__ csr, int e) {
  int i = (blockIdx.x * blockDim.x + threadIdx.x) * 2;
  if (i + 1 < e) {
    int2 s2 = *(const int2*)(src + i);
    int2 d2 = *(const int2*)(dst + i);
    float2 w2 = *(const float2*)(w + i);
    int2 r2 = *(const int2*)(rank + i);
    int p0 = rowptr[d2.x] + r2.x;
    int p1 = rowptr[d2.y] + r2.y;
    csr[p0] = make_int2(s2.x, __float_as_int(dinv[s2.x] * w2.x * dinv[d2.x]));
    csr[p1] = make_int2(s2.y, __float_as_int(dinv[s2.y] * w2.y * dinv[d2.y]));
  } else if (i < e) {
    int d = dst[i], s = src[i];
    int pos = rowptr[d] + rank[i];
    csr[pos] = make_int2(s, __float_as_int(dinv[s] * w[i] * dinv[d]));
  }
}

// ---------------- CSR aggregation + fused BN partial stats ----------------

template <int FOUT>
__global__ __launch_bounds__(256) void agg_csr_k(
    const unsigned short* __restrict__ hW, const int* __restrict__ rowptr,
    const int2* __restrict__ csr, const float* __restrict__ dinv,
    const float* __restrict__ b, unsigned short* __restrict__ out,
    float* __restrict__ psum, float* __restrict__ psq, int n) {
  constexpr int TPR = FOUT / 8;
  constexpr int RPB = 256 / TPR;
  const int t = threadIdx.x;
  const int j = t % TPR;
  const int rp = t / TPR;
  const int row = blockIdx.x * RPB + rp;
  const bool valid = row < n;

  float a[8] = {0.f, 0.f, 0.f, 0.f, 0.f, 0.f, 0.f, 0.f};
  if (valid) {
    const float di = dinv[row];
    const float c0 = di * di;
    {
      uint4 hu = *(const uint4*)(hW + (size_t)row * FOUT + j * 8);
      const float4 bb0 = *(const float4*)(b + j * 8);
      const float4 bb1 = *(const float4*)(b + j * 8 + 4);
      a[0] = bb0.x; a[1] = bb0.y; a[2] = bb0.z; a[3] = bb0.w;
      a[4] = bb1.x; a[5] = bb1.y; a[6] = bb1.z; a[7] = bb1.w;
      fma8(a, hu, c0);
    }
    const int e0 = rowptr[row], e1 = rowptr[row + 1];
    int ee = e0;
    for (; ee + 1 < e1; ee += 2) {
      const int2 d0 = csr[ee];
      const int2 d1 = csr[ee + 1];
      const uint4 u0 = *(const uint4*)(hW + (size_t)d0.x * FOUT + j * 8);
      const uint4 u1 = *(const uint4*)(hW + (size_t)d1.x * FOUT + j * 8);
      fma8(a, u0, __int_as_float(d0.y));
      fma8(a, u1, __int_as_float(d1.y));
    }
    if (ee < e1) {
      const int2 d0 = csr[ee];
      const uint4 u0 = *(const uint4*)(hW + (size_t)d0.x * FOUT + j * 8);
      fma8(a, u0, __int_as_float(d0.y));
    }
    uint4 o;
    o.x = pk_bf2(a[0], a[1]); o.y = pk_bf2(a[2], a[3]);
    o.z = pk_bf2(a[4], a[5]); o.w = pk_bf2(a[6], a[7]);
    *(uint4*)&out[(size_t)row * FOUT + j * 8] = o;
  }

  // fused BN partial stats (invalid rows contribute zeros; all threads sync)
  __shared__ float4 ls0[256], ls1[256], lq0[256], lq1[256];
  ls0[t] = make_float4(a[0], a[1], a[2], a[3]);
  ls1[t] = make_float4(a[4], a[5], a[6], a[7]);
  lq0[t] = make_float4(a[0] * a[0], a[1] * a[1], a[2] * a[2], a[3] * a[3]);
  lq1[t] = make_float4(a[4] * a[4], a[5] * a[5], a[6] * a[6], a[7] * a[7]);
  __syncthreads();
#pragma unroll
  for (int off = RPB / 2; off > 0; off >>= 1) {
    if (rp < off) {
      int o = off * TPR;
      float4 p, q;
      p = ls0[t]; q = ls0[t + o]; ls0[t] = make_float4(p.x + q.x, p.y + q.y, p.z + q.z, p.w + q.w);
      p = ls1[t]; q = ls1[t + o]; ls1[t] = make_float4(p.x + q.x, p.y + q.y, p.z + q.z, p.w + q.w);
      p = lq0[t]; q = lq0[t + o]; lq0[t] = make_float4(p.x + q.x, p.y + q.y, p.z + q.z, p.w + q.w);
      p = lq1[t]; q = lq1[t + o]; lq1[t] = make_float4(p.x + q.x, p.y + q.y, p.z + q.z, p.w + q.w);
    }
    __syncthreads();
  }
  if (rp == 0) {  // coalesced float4 partial stores
    *(float4*)&psum[(size_t)blockIdx.x * FOUT + j * 8] = ls0[j];
    *(float4*)&psum[(size_t)blockIdx.x * FOUT + j * 8 + 4] = ls1[j];
    *(float4*)&psq[(size_t)blockIdx.x * FOUT + j * 8] = lq0[j];
    *(float4*)&psq[(size_t)blockIdx.x * FOUT + j * 8 + 4] = lq1[j];
  }
}

// ---------------- per-column BN finalize: grid = FOUT blocks ----------------

template <int FOUT>
__global__ __launch_bounds__(256) void bn_fin_col_k(
    const float* __restrict__ psum, const float* __restrict__ psq,
    const float* __restrict__ g, const float* __restrict__ be,
    float* __restrict__ scale, float* __restrict__ shift, int nblk, int n) {
  const int col = blockIdx.x;
  const int t = threadIdx.x;
  float s = 0.f, q = 0.f;
  for (int i = t; i < nblk; i += 256) {
    s += psum[(size_t)i * FOUT + col];
    q += psq[(size_t)i * FOUT + col];
  }
  __shared__ float ss[256], qq[256];
  ss[t] = s;
  qq[t] = q;
  __syncthreads();
  for (int off = 128; off > 0; off >>= 1) {
    if (t < off) { ss[t] += ss[t + off]; qq[t] += qq[t + off]; }
    __syncthreads();
  }
  if (t == 0) {
    float inv_n = 1.0f / (float)n;
    float mu = ss[0] * inv_n;
    float var = qq[0] * inv_n - mu * mu;
    float sc = g[col] * rsqrtf(var + BN_EPS);
    scale[col] = sc;
    shift[col] = be[col] - mu * sc;
  }
}

// final BN apply: bf16 in (F=32), f32 out, no ReLU
__global__ void bn_apply32_k(const unsigned short* __restrict__ in,
                             const float* __restrict__ scale, const float* __restrict__ shift,
                             float* __restrict__ out, int n) {
  int gid = blockIdx.x * blockDim.x + threadIdx.x;
  int row = gid >> 2, j = gid & 3;
  if (row >= n) return;
  uint4 u = *(const uint4*)(in + (size_t)row * 32 + j * 8);
  float v[8] = {bf_lo(u.x), bf_hi(u.x), bf_lo(u.y), bf_hi(u.y),
                bf_lo(u.z), bf_hi(u.z), bf_lo(u.w), bf_hi(u.w)};
  const float4 sc0 = *(const float4*)(scale + j * 8);
  const float4 sc1 = *(const float4*)(scale + j * 8 + 4);
  const float4 sh0 = *(const float4*)(shift + j * 8);
  const float4 sh1 = *(const float4*)(shift + j * 8 + 4);
  float4 o0 = make_float4(v[0] * sc0.x + sh0.x, v[1] * sc0.y + sh0.y,
                          v[2] * sc0.z + sh0.z, v[3] * sc0.w + sh0.w);
  float4 o1 = make_float4(v[4] * sc1.x + sh1.x, v[5] * sc1.y + sh1.y,
                          v[6] * sc1.z + sh1.z, v[7] * sc1.w + sh1.w);
  float* p = out + (size_t)row * 32 + j * 8;
  *(float4*)p = o0;
  *(float4*)(p + 4) = o1;
}

// ---------------- launch ----------------

static inline size_t pad4(size_t v) { return (v + 3) & ~(size_t)3; }

extern "C" void kernel_launch(void* const* d_in, const int* in_sizes, int n_in,
                              void* d_out, int out_size, void* d_ws, size_t ws_size,
                              hipStream_t stream) {
  const int* x = (const int*)d_in[0];
  const int* ei = (const int*)d_in[1];
  const float* w = (const float*)d_in[2];
  const float* emb = (const float*)d_in[3];
  const float* W1 = (const float*)d_in[4];
  const float* b1 = (const float*)d_in[5];
  const float* g1 = (const float*)d_in[6];
  const float* be1 = (const float*)d_in[7];
  const float* W2 = (const float*)d_in[8];
  const float* b2 = (const float*)d_in[9];
  const float* g2 = (const float*)d_in[10];
  const float* be2 = (const float*)d_in[11];
  const float* W3 = (const float*)d_in[12];
  const float* b3 = (const float*)d_in[13];
  const float* g3 = (const float*)d_in[14];
  const float* be3 = (const float*)d_in[15];

  const int n = in_sizes[0];
  const int e = in_sizes[2];
  const int* src = ei;
  const int* dst = ei + e;

  float* ws = (float*)d_ws;
  size_t off = 0;
  unsigned short* bufA16 = (unsigned short*)(ws + off); off += pad4((size_t)n * 64);  // n*128 bf16 (hW)
  unsigned short* bufB16 = (unsigned short*)(ws + off); off += pad4((size_t)n * 64);  // n*128 bf16 (agg out)
  unsigned long long* packed = (unsigned long long*)(ws + off); off += pad4((size_t)n * 2);
  float* dinv = ws + off; off += pad4(n);
  int* rowptr = (int*)(ws + off); off += pad4(n + 1);
  int* rank = (int*)(ws + off); off += pad4(e);
  int2* csr = (int2*)(ws + off); off += pad4((size_t)e * 2);
  unsigned short* wt1 = (unsigned short*)(ws + off); off += 128 * 128 / 2;
  unsigned short* wt2 = (unsigned short*)(ws + off); off += 128 * 64 / 2;
  unsigned short* wt3 = (unsigned short*)(ws + off); off += 64 * 32 / 2;
  float* psum = ws + off; off += 400384;      // max nblk(3125) * 128 partials
  float* psq = ws + off; off += 400384;
  float* scale = ws + off; off += 128;
  float* shift = ws + off; off += 128;
  int* bsum = (int*)(ws + off); off += 256;

  const int B = 256;
  dim3 blk(B);
  const int nb = (n + 255) / 256;     // scan blocks (<=256 required; n=50k -> 196)
  const int e2 = (e + 1) / 2;         // 2 edges/thread grids
  const int gx = (n + 63) / 64;       // 64 rows per gemm block
  const int nblk1 = (n + 15) / 16;    // agg blocks, F=128
  const int nblk2 = (n + 31) / 32;    // F=64
  const int nblk3 = (n + 63) / 64;    // F=32

  // prep + CSR build (hist unpacked: 0-LDS, full occupancy for atomic throughput)
  prep_k<<<(n + B - 1) / B, blk, 0, stream>>>(W1, W2, W3, wt1, wt2, wt3, packed, n);
  hist64_k<<<(e2 + B - 1) / B, blk, 0, stream>>>(dst, w, packed, rank, e);
  scan_partial_k<<<nb, blk, 0, stream>>>(packed, bsum, dinv, n);
  scan_final_k<<<nb, blk, 0, stream>>>(packed, bsum, rowptr, n, nb);
  scatter_nb_k<<<(e2 + B - 1) / B, blk, 0, stream>>>(src, dst, w, rank, dinv, rowptr, csr, e);

  // ---- layer 1
  gemm_mfma_k<float, 128, 128, false, true><<<gx, blk, 0, stream>>>(emb, x, nullptr, nullptr, wt1, bufA16, n);
  agg_csr_k<128><<<nblk1, blk, 0, stream>>>(bufA16, rowptr, csr, dinv, b1, bufB16, psum, psq, n);
  bn_fin_col_k<128><<<128, blk, 0, stream>>>(psum, psq, g1, be1, scale, shift, nblk1, n);

  // ---- layer 2
  gemm_mfma_k<unsigned short, 128, 64, true, false><<<gx, blk, 0, stream>>>(bufB16, nullptr, scale, shift, wt2, bufA16, n);
  agg_csr_k<64><<<nblk2, blk, 0, stream>>>(bufA16, rowptr, csr, dinv, b2, bufB16, psum, psq, n);
  bn_fin_col_k<64><<<64, blk, 0, stream>>>(psum, psq, g2, be2, scale, shift, nblk2, n);

  // ---- layer 3
  gemm_mfma_k<unsigned short, 64, 32, true, false><<<gx, blk, 0, stream>>>(bufB16, nullptr, scale, shift, wt3, bufA16, n);
  agg_csr_k<32><<<nblk3, blk, 0, stream>>>(bufA16, rowptr, csr, dinv, b3, bufB16, psum, psq, n);
  bn_fin_col_k<32><<<32, blk, 0, stream>>>(psum, psq, g3, be3, scale, shift, nblk3, n);
  bn_apply32_k<<<((size_t)n * 4 + B - 1) / B, blk, 0, stream>>>(bufB16, scale, shift, (float*)d_out, n);
}

// Round 16
// 184.228 us; speedup vs baseline: 1.0536x; 1.0536x over previous
//
#include <hip/hip_runtime.h>
#include <hip/hip_bf16.h>

#define BN_EPS 1e-5f
#define FIXSCALE 16777216.0f            // 2^24
#define FIXINV   5.9604644775390625e-08 // 2^-24
#define LOWMASK  0xFFFFFFFFFFULL        // low 40 bits

typedef __attribute__((ext_vector_type(8))) short bf16x8;
typedef __attribute__((ext_vector_type(4))) float f32x4;

__device__ __forceinline__ unsigned short bfu(float v) {
  return __bfloat16_as_ushort(__float2bfloat16(v));
}
__device__ __forceinline__ unsigned int pk_bf2(float a, float b) {
  return (unsigned int)bfu(a) | ((unsigned int)bfu(b) << 16);
}
__device__ __forceinline__ float bf_lo(unsigned int u) { return __uint_as_float(u << 16); }
__device__ __forceinline__ float bf_hi(unsigned int u) { return __uint_as_float(u & 0xFFFF0000u); }

__device__ __forceinline__ void fma8(float* a, uint4 u, float c) {
  a[0] += bf_lo(u.x) * c; a[1] += bf_hi(u.x) * c;
  a[2] += bf_lo(u.y) * c; a[3] += bf_hi(u.y) * c;
  a[4] += bf_lo(u.z) * c; a[5] += bf_hi(u.z) * c;
  a[6] += bf_lo(u.w) * c; a[7] += bf_hi(u.w) * c;
}

__device__ __forceinline__ float4 load4(const float* p) { return *(const float4*)p; }
__device__ __forceinline__ float4 load4(const unsigned short* p) {
  uint2 u = *(const uint2*)p;
  return make_float4(bf_lo(u.x), bf_hi(u.x), bf_lo(u.y), bf_hi(u.y));
}

template <int FIN, int FOUT>
constexpr int gemm_lds_bytes() {
  int stage = (64 * (FIN + 8) + FOUT * (FIN + 8)) * 2;  // shorts*2 = bytes
  int cb = 64 * (FOUT + 4) * 4;
  return stage > cb ? stage : cb;
}

// ---------------- prep: zero packed + weight transpose->bf16 ----------------

__global__ void prep_k(const float* __restrict__ W1, const float* __restrict__ W2,
                       const float* __restrict__ W3, unsigned short* __restrict__ wt1,
                       unsigned short* __restrict__ wt2, unsigned short* __restrict__ wt3,
                       unsigned long long* __restrict__ packed, int n) {
  int idx = blockIdx.x * 256 + threadIdx.x;
  if (idx < n) packed[idx] = 0ULL;
  if (idx < 128 * 128) {
    int c = idx >> 7, k = idx & 127;
    wt1[idx] = bfu(W1[k * 128 + c]);
  } else if (idx < 128 * 128 + 128 * 64) {
    int i2 = idx - 128 * 128;
    int c = i2 >> 7, k = i2 & 127;  // wt2: [64][128]
    wt2[i2] = bfu(W2[k * 64 + c]);
  } else if (idx < 128 * 128 + 128 * 64 + 64 * 32) {
    int i2 = idx - 128 * 128 - 128 * 64;
    int c = i2 >> 6, k = i2 & 63;   // wt3: [32][64]
    wt3[i2] = bfu(W3[k * 32 + c]);
  }
}

// ---------------- packed dispatch: slim layer-1 GEMM (17.4KB LDS) + hist ----------------
// Slim gemm: Ht staged (coalescing is load-bearing); B-fragments read directly
// from the 32KB L2-resident wt1; C flushed in two 32-row phases through an LDS
// buffer overlaying dead Ht. Small static LDS -> hist blocks keep ~8 blocks/CU
// of atomic concurrency (round-14's 52KB reservation was the defect).

__global__ __launch_bounds__(256) void hist_gemm1_k(
    const float* __restrict__ emb, const int* __restrict__ x,
    const unsigned short* __restrict__ wt1, unsigned short* __restrict__ outA,
    const int* __restrict__ dst, const float* __restrict__ w,
    unsigned long long* __restrict__ packed, int* __restrict__ rank,
    int n, int e, int gx) {
  constexpr int FIN = 128, FOUT = 128;
  constexpr int C4 = FIN / 4;     // 32
  constexpr int ldH = FIN + 8;    // 136 shorts
  constexpr int ldC = FOUT + 4;   // 132 floats
  constexpr int NCT = FOUT / 16;  // 8
  constexpr int NK = FIN / 32;    // 4
  __shared__ __align__(16) char smem[64 * ldH * 2];  // 17408 B
  unsigned short* Ht = (unsigned short*)smem;
  float* Cs = (float*)smem;       // 32 rows x 132 floats = 16896 B, overlays Ht

  if ((int)blockIdx.x >= gx) {
    // ---- hist role (no LDS use)
    int i = ((blockIdx.x - gx) * 256 + threadIdx.x) * 2;
    if (i + 1 < e) {
      int2 d2 = *(const int2*)(dst + i);
      float2 w2 = *(const float2*)(w + i);
      unsigned long long a0 = (1ULL << 40) | (unsigned long long)__float2uint_rn(w2.x * FIXSCALE);
      unsigned long long a1 = (1ULL << 40) | (unsigned long long)__float2uint_rn(w2.y * FIXSCALE);
      unsigned long long o0 = atomicAdd(&packed[d2.x], a0);
      unsigned long long o1 = atomicAdd(&packed[d2.y], a1);
      *(int2*)(rank + i) = make_int2((int)(o0 >> 40), (int)(o1 >> 40));
    } else if (i < e) {
      unsigned long long fw = (unsigned long long)__float2uint_rn(w[i] * FIXSCALE);
      unsigned long long old = atomicAdd(&packed[dst[i]], (1ULL << 40) | fw);
      rank[i] = (int)(old >> 40);
    }
    return;
  }

  // ---- gemm role
  const int t = threadIdx.x;
  const int r0 = blockIdx.x * 64;

  constexpr int NH = 64 * C4 / 256;  // 8
#pragma unroll
  for (int i = 0; i < NH; ++i) {
    int idx = t + 256 * i;
    int r = idx / C4, c4 = idx % C4;
    int gr = r0 + r;
    if (gr < n) {
      int srow = x[gr];
      float4 v = *(const float4*)(emb + (size_t)srow * FIN + c4 * 4);
      ushort4 p;
      p.x = bfu(v.x); p.y = bfu(v.y); p.z = bfu(v.z); p.w = bfu(v.w);
      *(ushort4*)&Ht[r * ldH + c4 * 4] = p;
    }
  }
  __syncthreads();

  const int wv = t >> 6;
  const int l = t & 63;
  const int l15 = l & 15;
  const int kg = l >> 4;
  const int arow = wv * 16 + l15;

  f32x4 acc[NCT];
#pragma unroll
  for (int c = 0; c < NCT; ++c) acc[c] = (f32x4){0.f, 0.f, 0.f, 0.f};

#pragma unroll
  for (int kk = 0; kk < NK; ++kk) {
    bf16x8 a = *(const bf16x8*)&Ht[arow * ldH + kk * 32 + kg * 8];
#pragma unroll
    for (int c = 0; c < NCT; ++c) {
      bf16x8 b = *(const bf16x8*)&wt1[(size_t)(c * 16 + l15) * FIN + kk * 32 + kg * 8];
      acc[c] = __builtin_amdgcn_mfma_f32_16x16x32_bf16(a, b, acc[c], 0, 0, 0);
    }
  }
  __syncthreads();  // Ht dead; Cs overlays it

  // two-phase C flush: rows 0-31 (waves 0,1), then rows 32-63 (waves 2,3)
#pragma unroll
  for (int ph = 0; ph < 2; ++ph) {
    if ((wv >> 1) == ph) {
#pragma unroll
      for (int c = 0; c < NCT; ++c)
#pragma unroll
        for (int m = 0; m < 4; ++m)
          Cs[((wv & 1) * 16 + kg * 4 + m) * ldC + c * 16 + l15] = acc[c][m];
    }
    __syncthreads();
#pragma unroll
    for (int i = 0; i < 2; ++i) {  // 32 rows * 16 uint4 / 256 threads
      int u = t + 256 * i;
      int r = u / (FOUT / 8), c8 = u % (FOUT / 8);
      int gr = r0 + ph * 32 + r;
      if (gr < n) {
        const float* p = &Cs[r * ldC + c8 * 8];
        float4 v0 = *(const float4*)p;
        float4 v1 = *(const float4*)(p + 4);
        uint4 o;
        o.x = pk_bf2(v0.x, v0.y); o.y = pk_bf2(v0.z, v0.w);
        o.z = pk_bf2(v1.x, v1.y); o.w = pk_bf2(v1.z, v1.w);
        *(uint4*)&outA[(size_t)gr * FOUT + c8 * 8] = o;
      }
    }
    if (ph == 0) __syncthreads();  // before waves 2,3 overwrite Cs
  }
}

// ---------------- staged MFMA GEMM (layers 2,3) ----------------

template <typename TIN, int FIN, int FOUT, bool BNIN>
__global__ __launch_bounds__(256) void gemm_mfma_k(
    const TIN* __restrict__ H, const float* __restrict__ scale, const float* __restrict__ shift,
    const unsigned short* __restrict__ WtG, unsigned short* __restrict__ out, int n) {
  constexpr int C4 = FIN / 4;
  constexpr int ldH = FIN + 8;
  constexpr int ldW = FIN + 8;
  constexpr int ldC = FOUT + 4;
  constexpr int NCT = FOUT / 16;
  constexpr int NK = FIN / 32;
  constexpr int HT_SH = 64 * ldH;

  __shared__ __align__(16) char smem[gemm_lds_bytes<FIN, FOUT>()];
  unsigned short* Ht = (unsigned short*)smem;
  unsigned short* Wt = (unsigned short*)smem + HT_SH;
  float* Cs = (float*)smem;

  const int t = threadIdx.x;
  const int r0 = blockIdx.x * 64;

  constexpr int NH = 64 * C4 / 256;
#pragma unroll
  for (int i = 0; i < NH; ++i) {
    int idx = t + 256 * i;
    int r = idx / C4, c4 = idx % C4;
    int gr = r0 + r;
    if (gr < n) {
      float4 v = load4(H + (size_t)gr * FIN + c4 * 4);
      if (BNIN) {
        float4 sc = *(const float4*)(scale + c4 * 4);
        float4 sh = *(const float4*)(shift + c4 * 4);
        v.x = fmaxf(v.x * sc.x + sh.x, 0.f);
        v.y = fmaxf(v.y * sc.y + sh.y, 0.f);
        v.z = fmaxf(v.z * sc.z + sh.z, 0.f);
        v.w = fmaxf(v.w * sc.w + sh.w, 0.f);
      }
      ushort4 p;
      p.x = bfu(v.x); p.y = bfu(v.y); p.z = bfu(v.z); p.w = bfu(v.w);
      *(ushort4*)&Ht[r * ldH + c4 * 4] = p;
    }
  }
  constexpr int NWU = FOUT * FIN / 8 / 256;
#pragma unroll
  for (int i = 0; i < NWU; ++i) {
    int idx = t + 256 * i;
    int wr = idx / (FIN / 8), w8 = idx % (FIN / 8);
    *(uint4*)&Wt[wr * ldW + w8 * 8] = *(const uint4*)&WtG[wr * FIN + w8 * 8];
  }
  __syncthreads();

  const int w = t >> 6;
  const int l = t & 63;
  const int l15 = l & 15;
  const int kg = l >> 4;
  const int arow = w * 16 + l15;

  f32x4 acc[NCT];
#pragma unroll
  for (int c = 0; c < NCT; ++c) acc[c] = (f32x4){0.f, 0.f, 0.f, 0.f};

#pragma unroll
  for (int kk = 0; kk < NK; ++kk) {
    bf16x8 a = *(const bf16x8*)&Ht[arow * ldH + kk * 32 + kg * 8];
#pragma unroll
    for (int c = 0; c < NCT; ++c) {
      bf16x8 b = *(const bf16x8*)&Wt[(c * 16 + l15) * ldW + kk * 32 + kg * 8];
      acc[c] = __builtin_amdgcn_mfma_f32_16x16x32_bf16(a, b, acc[c], 0, 0, 0);
    }
  }
  __syncthreads();

#pragma unroll
  for (int c = 0; c < NCT; ++c)
#pragma unroll
    for (int m = 0; m < 4; ++m)
      Cs[(w * 16 + kg * 4 + m) * ldC + c * 16 + l15] = acc[c][m];
  __syncthreads();

  constexpr int NU = 64 * FOUT / 8 / 256;
#pragma unroll
  for (int i = 0; i < NU; ++i) {
    int u = t + 256 * i;
    int r = u / (FOUT / 8), c8 = u % (FOUT / 8);
    int gr = r0 + r;
    if (gr < n) {
      const float* p = &Cs[r * ldC + c8 * 8];
      float4 v0 = *(const float4*)p;
      float4 v1 = *(const float4*)(p + 4);
      uint4 o;
      o.x = pk_bf2(v0.x, v0.y); o.y = pk_bf2(v0.z, v0.w);
      o.z = pk_bf2(v1.x, v1.y); o.w = pk_bf2(v1.z, v1.w);
      *(uint4*)&out[(size_t)gr * FOUT + c8 * 8] = o;
    }
  }
}

// ---------------- scans + scatter ----------------

__global__ void scan_partial_k(const unsigned long long* __restrict__ packed,
                               int* __restrict__ bsum, float* __restrict__ dinv, int n) {
  __shared__ int s[256];
  int idx = blockIdx.x * 256 + threadIdx.x;
  unsigned long long p = (idx < n) ? packed[idx] : 0ULL;
  if (idx < n)
    dinv[idx] = rsqrtf(1.0f + (float)((double)(p & LOWMASK) * FIXINV));
  s[threadIdx.x] = (int)(p >> 40);
  __syncthreads();
  for (int off = 128; off > 0; off >>= 1) {
    if (threadIdx.x < off) s[threadIdx.x] += s[threadIdx.x + off];
    __syncthreads();
  }
  if (threadIdx.x == 0) bsum[blockIdx.x] = s[0];
}

__global__ void scan_final_k(const unsigned long long* __restrict__ packed,
                             const int* __restrict__ bsum, int* __restrict__ rowptr,
                             int n, int nb) {
  __shared__ int sb[256];
  __shared__ int s[256];
  const int b = blockIdx.x, t = threadIdx.x;

  int bv = (t < nb) ? bsum[t] : 0;
  sb[t] = bv;
  __syncthreads();
  for (int off = 1; off < 256; off <<= 1) {
    int u = (t >= off) ? sb[t - off] : 0;
    __syncthreads();
    sb[t] += u;
    __syncthreads();
  }
  const int blockbase = (b == 0) ? 0 : sb[b - 1];
  if (b == 0 && t == 0) rowptr[n] = sb[nb - 1];

  int idx = b * 256 + t;
  int v = (idx < n) ? (int)(packed[idx] >> 40) : 0;
  s[t] = v;
  __syncthreads();
  for (int off = 1; off < 256; off <<= 1) {
    int u = (t >= off) ? s[t - off] : 0;
    __syncthreads();
    s[t] += u;
    __syncthreads();
  }
  if (idx < n) rowptr[idx] = blockbase + s[t] - v;
}

__global__ void scatter_nb_k(const int* __restrict__ src, const int* __restrict__ dst,
                             const float* __restrict__ w, const int* __restrict__ rank,
                             const float* __restrict__ dinv, const int* __restrict__ rowptr,
                             int2* __restrict__ csr, int e) {
  int i = (blockIdx.x * blockDim.x + threadIdx.x) * 2;
  if (i + 1 < e) {
    int2 s2 = *(const int2*)(src + i);
    int2 d2 = *(const int2*)(dst + i);
    float2 w2 = *(const float2*)(w + i);
    int2 r2 = *(const int2*)(rank + i);
    int p0 = rowptr[d2.x] + r2.x;
    int p1 = rowptr[d2.y] + r2.y;
    csr[p0] = make_int2(s2.x, __float_as_int(dinv[s2.x] * w2.x * dinv[d2.x]));
    csr[p1] = make_int2(s2.y, __float_as_int(dinv[s2.y] * w2.y * dinv[d2.y]));
  } else if (i < e) {
    int d = dst[i], s = src[i];
    int pos = rowptr[d] + rank[i];
    csr[pos] = make_int2(s, __float_as_int(dinv[s] * w[i] * dinv[d]));
  }
}

// ---------------- CSR aggregation + fused BN partial stats ----------------

template <int FOUT>
__global__ __launch_bounds__(256) void agg_csr_k(
    const unsigned short* __restrict__ hW, const int* __restrict__ rowptr,
    const int2* __restrict__ csr, const float* __restrict__ dinv,
    const float* __restrict__ b, unsigned short* __restrict__ out,
    float* __restrict__ psum, float* __restrict__ psq, int n) {
  constexpr int TPR = FOUT / 8;
  constexpr int RPB = 256 / TPR;
  const int t = threadIdx.x;
  const int j = t % TPR;
  const int rp = t / TPR;
  const int row = blockIdx.x * RPB + rp;
  const bool valid = row < n;

  float a[8] = {0.f, 0.f, 0.f, 0.f, 0.f, 0.f, 0.f, 0.f};
  if (valid) {
    const float di = dinv[row];
    const float c0 = di * di;
    {
      uint4 hu = *(const uint4*)(hW + (size_t)row * FOUT + j * 8);
      const float4 bb0 = *(const float4*)(b + j * 8);
      const float4 bb1 = *(const float4*)(b + j * 8 + 4);
      a[0] = bb0.x; a[1] = bb0.y; a[2] = bb0.z; a[3] = bb0.w;
      a[4] = bb1.x; a[5] = bb1.y; a[6] = bb1.z; a[7] = bb1.w;
      fma8(a, hu, c0);
    }
    const int e0 = rowptr[row], e1 = rowptr[row + 1];
    int ee = e0;
    for (; ee + 1 < e1; ee += 2) {
      const int2 d0 = csr[ee];
      const int2 d1 = csr[ee + 1];
      const uint4 u0 = *(const uint4*)(hW + (size_t)d0.x * FOUT + j * 8);
      const uint4 u1 = *(const uint4*)(hW + (size_t)d1.x * FOUT + j * 8);
      fma8(a, u0, __int_as_float(d0.y));
      fma8(a, u1, __int_as_float(d1.y));
    }
    if (ee < e1) {
      const int2 d0 = csr[ee];
      const uint4 u0 = *(const uint4*)(hW + (size_t)d0.x * FOUT + j * 8);
      fma8(a, u0, __int_as_float(d0.y));
    }
    uint4 o;
    o.x = pk_bf2(a[0], a[1]); o.y = pk_bf2(a[2], a[3]);
    o.z = pk_bf2(a[4], a[5]); o.w = pk_bf2(a[6], a[7]);
    *(uint4*)&out[(size_t)row * FOUT + j * 8] = o;
  }

  __shared__ float4 ls0[256], ls1[256], lq0[256], lq1[256];
  ls0[t] = make_float4(a[0], a[1], a[2], a[3]);
  ls1[t] = make_float4(a[4], a[5], a[6], a[7]);
  lq0[t] = make_float4(a[0] * a[0], a[1] * a[1], a[2] * a[2], a[3] * a[3]);
  lq1[t] = make_float4(a[4] * a[4], a[5] * a[5], a[6] * a[6], a[7] * a[7]);
  __syncthreads();
#pragma unroll
  for (int off = RPB / 2; off > 0; off >>= 1) {
    if (rp < off) {
      int o = off * TPR;
      float4 p, q;
      p = ls0[t]; q = ls0[t + o]; ls0[t] = make_float4(p.x + q.x, p.y + q.y, p.z + q.z, p.w + q.w);
      p = ls1[t]; q = ls1[t + o]; ls1[t] = make_float4(p.x + q.x, p.y + q.y, p.z + q.z, p.w + q.w);
      p = lq0[t]; q = lq0[t + o]; lq0[t] = make_float4(p.x + q.x, p.y + q.y, p.z + q.z, p.w + q.w);
      p = lq1[t]; q = lq1[t + o]; lq1[t] = make_float4(p.x + q.x, p.y + q.y, p.z + q.z, p.w + q.w);
    }
    __syncthreads();
  }
  if (rp == 0) {
    *(float4*)&psum[(size_t)blockIdx.x * FOUT + j * 8] = ls0[j];
    *(float4*)&psum[(size_t)blockIdx.x * FOUT + j * 8 + 4] = ls1[j];
    *(float4*)&psq[(size_t)blockIdx.x * FOUT + j * 8] = lq0[j];
    *(float4*)&psq[(size_t)blockIdx.x * FOUT + j * 8 + 4] = lq1[j];
  }
}

// ---------------- per-column BN finalize: grid = FOUT blocks ----------------

template <int FOUT>
__global__ __launch_bounds__(256) void bn_fin_col_k(
    const float* __restrict__ psum, const float* __restrict__ psq,
    const float* __restrict__ g, const float* __restrict__ be,
    float* __restrict__ scale, float* __restrict__ shift, int nblk, int n) {
  const int col = blockIdx.x;
  const int t = threadIdx.x;
  float s = 0.f, q = 0.f;
  for (int i = t; i < nblk; i += 256) {
    s += psum[(size_t)i * FOUT + col];
    q += psq[(size_t)i * FOUT + col];
  }
  __shared__ float ss[256], qq[256];
  ss[t] = s;
  qq[t] = q;
  __syncthreads();
  for (int off = 128; off > 0; off >>= 1) {
    if (t < off) { ss[t] += ss[t + off]; qq[t] += qq[t + off]; }
    __syncthreads();
  }
  if (t == 0) {
    float inv_n = 1.0f / (float)n;
    float mu = ss[0] * inv_n;
    float var = qq[0] * inv_n - mu * mu;
    float sc = g[col] * rsqrtf(var + BN_EPS);
    scale[col] = sc;
    shift[col] = be[col] - mu * sc;
  }
}

// final BN apply: bf16 in (F=32), f32 out, no ReLU
__global__ void bn_apply32_k(const unsigned short* __restrict__ in,
                             const float* __restrict__ scale, const float* __restrict__ shift,
                             float* __restrict__ out, int n) {
  int gid = blockIdx.x * blockDim.x + threadIdx.x;
  int row = gid >> 2, j = gid & 3;
  if (row >= n) return;
  uint4 u = *(const uint4*)(in + (size_t)row * 32 + j * 8);
  float v[8] = {bf_lo(u.x), bf_hi(u.x), bf_lo(u.y), bf_hi(u.y),
                bf_lo(u.z), bf_hi(u.z), bf_lo(u.w), bf_hi(u.w)};
  const float4 sc0 = *(const float4*)(scale + j * 8);
  const float4 sc1 = *(const float4*)(scale + j * 8 + 4);
  const float4 sh0 = *(const float4*)(shift + j * 8);
  const float4 sh1 = *(const float4*)(shift + j * 8 + 4);
  float4 o0 = make_float4(v[0] * sc0.x + sh0.x, v[1] * sc0.y + sh0.y,
                          v[2] * sc0.z + sh0.z, v[3] * sc0.w + sh0.w);
  float4 o1 = make_float4(v[4] * sc1.x + sh1.x, v[5] * sc1.y + sh1.y,
                          v[6] * sc1.z + sh1.z, v[7] * sc1.w + sh1.w);
  float* p = out + (size_t)row * 32 + j * 8;
  *(float4*)p = o0;
  *(float4*)(p + 4) = o1;
}

// ---------------- launch ----------------

static inline size_t pad4(size_t v) { return (v + 3) & ~(size_t)3; }

extern "C" void kernel_launch(void* const* d_in, const int* in_sizes, int n_in,
                              void* d_out, int out_size, void* d_ws, size_t ws_size,
                              hipStream_t stream) {
  const int* x = (const int*)d_in[0];
  const int* ei = (const int*)d_in[1];
  const float* w = (const float*)d_in[2];
  const float* emb = (const float*)d_in[3];
  const float* W1 = (const float*)d_in[4];
  const float* b1 = (const float*)d_in[5];
  const float* g1 = (const float*)d_in[6];
  const float* be1 = (const float*)d_in[7];
  const float* W2 = (const float*)d_in[8];
  const float* b2 = (const float*)d_in[9];
  const float* g2 = (const float*)d_in[10];
  const float* be2 = (const float*)d_in[11];
  const float* W3 = (const float*)d_in[12];
  const float* b3 = (const float*)d_in[13];
  const float* g3 = (const float*)d_in[14];
  const float* be3 = (const float*)d_in[15];

  const int n = in_sizes[0];
  const int e = in_sizes[2];
  const int* src = ei;
  const int* dst = ei + e;

  float* ws = (float*)d_ws;
  size_t off = 0;
  unsigned short* bufA16 = (unsigned short*)(ws + off); off += pad4((size_t)n * 64);  // n*128 bf16 (hW)
  unsigned short* bufB16 = (unsigned short*)(ws + off); off += pad4((size_t)n * 64);  // n*128 bf16 (agg out)
  unsigned long long* packed = (unsigned long long*)(ws + off); off += pad4((size_t)n * 2);
  float* dinv = ws + off; off += pad4(n);
  int* rowptr = (int*)(ws + off); off += pad4(n + 1);
  int* rank = (int*)(ws + off); off += pad4(e);
  int2* csr = (int2*)(ws + off); off += pad4((size_t)e * 2);
  unsigned short* wt1 = (unsigned short*)(ws + off); off += 128 * 128 / 2;
  unsigned short* wt2 = (unsigned short*)(ws + off); off += 128 * 64 / 2;
  unsigned short* wt3 = (unsigned short*)(ws + off); off += 64 * 32 / 2;
  float* psum = ws + off; off += 400384;      // max nblk(3125) * 128 partials
  float* psq = ws + off; off += 400384;
  float* scale = ws + off; off += 128;
  float* shift = ws + off; off += 128;
  int* bsum = (int*)(ws + off); off += 256;

  const int B = 256;
  dim3 blk(B);
  const int nb = (n + 255) / 256;     // scan blocks (<=256 required; n=50k -> 196)
  const int e2 = (e + 1) / 2;         // 2 edges/thread grids
  const int gx = (n + 63) / 64;       // 64 rows per gemm block
  const int nblk1 = (n + 15) / 16;    // agg blocks, F=128
  const int nblk2 = (n + 31) / 32;    // F=64
  const int nblk3 = (n + 63) / 64;    // F=32

  // prep, then packed [slim gemm1 || hist]
  prep_k<<<(n + B - 1) / B, blk, 0, stream>>>(W1, W2, W3, wt1, wt2, wt3, packed, n);
  hist_gemm1_k<<<gx + (e2 + B - 1) / B, blk, 0, stream>>>(emb, x, wt1, bufA16, dst, w, packed, rank, n, e, gx);
  scan_partial_k<<<nb, blk, 0, stream>>>(packed, bsum, dinv, n);
  scan_final_k<<<nb, blk, 0, stream>>>(packed, bsum, rowptr, n, nb);
  scatter_nb_k<<<(e2 + B - 1) / B, blk, 0, stream>>>(src, dst, w, rank, dinv, rowptr, csr, e);

  // ---- layer 1 (gemm1 done in packed dispatch)
  agg_csr_k<128><<<nblk1, blk, 0, stream>>>(bufA16, rowptr, csr, dinv, b1, bufB16, psum, psq, n);
  bn_fin_col_k<128><<<128, blk, 0, stream>>>(psum, psq, g1, be1, scale, shift, nblk1, n);

  // ---- layer 2
  gemm_mfma_k<unsigned short, 128, 64, true><<<gx, blk, 0, stream>>>(bufB16, scale, shift, wt2, bufA16, n);
  agg_csr_k<64><<<nblk2, blk, 0, stream>>>(bufA16, rowptr, csr, dinv, b2, bufB16, psum, psq, n);
  bn_fin_col_k<64><<<64, blk, 0, stream>>>(psum, psq, g2, be2, scale, shift, nblk2, n);

  // ---- layer 3
  gemm_mfma_k<unsigned short, 64, 32, true><<<gx, blk, 0, stream>>>(bufB16, scale, shift, wt3, bufA16, n);
  agg_csr_k<32><<<nblk3, blk, 0, stream>>>(bufA16, rowptr, csr, dinv, b3, bufB16, psum, psq, n);
  bn_fin_col_k<32><<<32, blk, 0, stream>>>(psum, psq, g3, be3, scale, shift, nblk3, n);
  bn_apply32_k<<<((size_t)n * 4 + B - 1) / B, blk, 0, stream>>>(bufB16, scale, shift, (float*)d_out, n);
}